// Round 15
// baseline (71.989 us; speedup 1.0000x reference)
//
#include <hip/hip_runtime.h>
#include <hip/hip_bf16.h>
#include <stdint.h>

// out_re[b,i] = sum_{j,l} Re{ x[b,j,l]*k[i,j]*conj(k[i,l]) },  d_out = Re only.
//   T[i,j] = sum_l K[i,l]X[j,l]:  T_re = P·R + Q·M ; T_im = P·M + Q·(-R)
//   out_re[b,i] = sum_j T_re*p[i,j] - T_im*q[i,j]
// Round-15: LDS-port-bound fix (r12-14 floor = 1.25MB LDS reads/batch/CU).
// Partition: wave (iw=w&3, jh=w>>2) owns i in [32iw,+32) x j-half jh.
//  - K-A frags: 64 VGPRs, loaded once (K LDS traffic: 256KB/batch -> 0)
//  - X read by 4 waves not 8 (1MB -> 512KB/batch)
//  - epilogue weights in 32 VGPRs (u16 LDS gathers -> 0)
// LDS = 3 x 32KB X buffers + 1KB partials = 99KB. STAGE/read/swizzle/vmcnt
// ledger identical to r14 (verified): WAITV(8) steady, 8/8/4/0 tail, stores
// only make waits conservatively deeper. SIMD k hosts waves {k, k+4} = one
// jh0 + one jh1 -> every SIMD has an active compute wave each phase.

typedef __attribute__((ext_vector_type(8))) __bf16 bf16x8;
typedef __attribute__((ext_vector_type(4))) float f32x4;
typedef __attribute__((ext_vector_type(4))) unsigned int u32x4;

#define EDIM 128
#define NBAT 8
#define XBUF 32768
#define XM_OFF 16384
#define PART_OFF (3 * XBUF)
#define LDS_BYTES (3 * XBUF + 1024)

static __device__ inline bf16x8 neg8(bf16x8 v) {
    u32x4 u = __builtin_bit_cast(u32x4, v);
    u ^= (u32x4){0x80008000u, 0x80008000u, 0x80008000u, 0x80008000u};
    return __builtin_bit_cast(bf16x8, u);
}

#define ASG(p) (__attribute__((address_space(1))) const void*)(p)
#define ASL(p) (__attribute__((address_space(3))) void*)(p)
#define WAITV(N_) asm volatile("s_waitcnt vmcnt(" #N_ ")" ::: "memory")
#define BARRIER() asm volatile("s_barrier" ::: "memory")

__global__ __launch_bounds__(512, 2) void qmeas_kernel(
    const float* __restrict__ R, const float* __restrict__ M,
    const float* __restrict__ Kern, float* __restrict__ out, int nout)
{
    extern __shared__ unsigned char smem[];   // X0 | X1 | X2 | part(1KB)

    const int t    = threadIdx.x;
    const int lane = t & 63;
    const int w    = t >> 6;
    const int li   = lane & 15;
    const int s    = lane >> 4;    // 0..3
    const int rhi  = lane >> 5;    // 0..1 (staging row-within-pair)
    const int iw   = w & 3;        // i-block: i in [32iw, 32iw+32)
    const int jh   = w >> 2;       // j-half: j in [64jh, 64jh+64)
    const int key  = li & 7;       // X swizzle key on read
    const int bat0 = blockIdx.x * NBAT;

    // ---- K-A fragments in registers (64 VGPRs), loaded once ----
    // pa[nn][u]: lane (li,s) holds K[(2iw+nn)*16+li][u*32+s*8+e]
    bf16x8 pa[2][4], qa[2][4];
#pragma unroll
    for (int nn = 0; nn < 2; ++nn) {
#pragma unroll
        for (int u = 0; u < 4; ++u) {
            const int i = (iw * 2 + nn) * 16 + li;
            const float* g = Kern + (((size_t)i * EDIM + u * 32 + s * 8) << 1);
            f32x4 f0 = *(const f32x4*)(g);
            f32x4 f1 = *(const f32x4*)(g + 4);
            f32x4 f2 = *(const f32x4*)(g + 8);
            f32x4 f3 = *(const f32x4*)(g + 12);
            bf16x8 pv, qv;
            pv[0] = (__bf16)f0[0]; qv[0] = (__bf16)f0[1];
            pv[1] = (__bf16)f0[2]; qv[1] = (__bf16)f0[3];
            pv[2] = (__bf16)f1[0]; qv[2] = (__bf16)f1[1];
            pv[3] = (__bf16)f1[2]; qv[3] = (__bf16)f1[3];
            pv[4] = (__bf16)f2[0]; qv[4] = (__bf16)f2[1];
            pv[5] = (__bf16)f2[2]; qv[5] = (__bf16)f2[3];
            pv[6] = (__bf16)f3[0]; qv[6] = (__bf16)f3[1];
            pv[7] = (__bf16)f3[2]; qv[7] = (__bf16)f3[3];
            pa[nn][u] = pv;
            qa[nn][u] = qv;
        }
    }

    // ---- epilogue weights in registers (32 VGPRs): kwp[nn][jt_h][2r]=p,[2r+1]=q
    // holds k[(2iw+nn)*16+s*4+r][jh*64 + jt_h*16 + li]
    const float2* K2 = (const float2*)Kern;
    bf16x8 kwp[2][4];
#pragma unroll
    for (int nn = 0; nn < 2; ++nn) {
#pragma unroll
        for (int jt = 0; jt < 4; ++jt) {
#pragma unroll
            for (int r = 0; r < 4; ++r) {
                float2 kv = K2[(size_t)((iw * 2 + nn) * 16 + s * 4 + r) * EDIM
                               + jh * 64 + jt * 16 + li];
                kwp[nn][jt][2 * r]     = (__bf16)kv.x;
                kwp[nn][jt][2 * r + 1] = (__bf16)kv.y;
            }
        }
    }

    // stage j-quarter q_ (rows [32q_,+32), full l) of batch base xb_ into xo_
#define STAGE_X(xb_, q_, xo_)                                                   \
    do {                                                                        \
        unsigned char* db_ = smem + (xo_);                                      \
        _Pragma("unroll")                                                       \
        for (int k2 = 0; k2 < 2; ++k2) {                                        \
            int rloc = (w << 2) + (k2 << 1);                                    \
            int rowg = (q_) * 32 + rloc + rhi;                                  \
            int colf = ((lane & 31) ^ ((rloc + rhi) & 7)) << 2;                 \
            const float* sR_ = R + (xb_) + (size_t)rowg * EDIM + colf;          \
            const float* sM_ = M + (xb_) + (size_t)rowg * EDIM + colf;          \
            unsigned char* d_ = db_ + rloc * 512;                               \
            __builtin_amdgcn_global_load_lds(ASG(sR_), ASL(d_), 16, 0, 0);      \
            __builtin_amdgcn_global_load_lds(ASG(sM_), ASL(d_ + XM_OFF), 16, 0, 0); \
        }                                                                       \
    } while (0)

    // compute+fold quarter p_ from LDS offset xo_ (active iff jh == p_>>1)
#define COMPUTE_FOLD(p_, xo_)                                                   \
    if (jh == ((p_) >> 1)) {                                                    \
        const unsigned char* Xb = smem + (xo_);                                 \
        f32x4 are[2][2], aim[2][2];                                             \
        _Pragma("unroll")                                                       \
        for (int nn = 0; nn < 2; ++nn) {                                        \
            are[nn][0] = (f32x4){0.f,0.f,0.f,0.f};                              \
            are[nn][1] = (f32x4){0.f,0.f,0.f,0.f};                              \
            aim[nn][0] = (f32x4){0.f,0.f,0.f,0.f};                              \
            aim[nn][1] = (f32x4){0.f,0.f,0.f,0.f};                              \
        }                                                                       \
        _Pragma("unroll")                                                       \
        for (int u = 0; u < 4; ++u) {                                           \
            _Pragma("unroll")                                                   \
            for (int jt = 0; jt < 2; ++jt) {                                    \
                int rl = (jt << 4) + li;                                        \
                int c0 = (u << 3) + (s << 1);                                   \
                int a0 = rl * 512 + ((c0 ^ key) << 4);                          \
                int a1 = rl * 512 + (((c0 + 1) ^ key) << 4);                    \
                f32x4 r0 = *(const f32x4*)(Xb + a0);                            \
                f32x4 r1 = *(const f32x4*)(Xb + a1);                            \
                f32x4 m0 = *(const f32x4*)(Xb + XM_OFF + a0);                   \
                f32x4 m1 = *(const f32x4*)(Xb + XM_OFF + a1);                   \
                bf16x8 xr, xm;                                                  \
                _Pragma("unroll")                                               \
                for (int e = 0; e < 4; ++e) {                                   \
                    xr[e] = (__bf16)r0[e]; xr[4 + e] = (__bf16)r1[e];           \
                    xm[e] = (__bf16)m0[e]; xm[4 + e] = (__bf16)m1[e];           \
                }                                                               \
                bf16x8 xrn = neg8(xr);                                          \
                _Pragma("unroll")                                               \
                for (int nn = 0; nn < 2; ++nn) {                                \
                    are[nn][jt] = __builtin_amdgcn_mfma_f32_16x16x32_bf16(pa[nn][u], xr,  are[nn][jt], 0, 0, 0); \
                    are[nn][jt] = __builtin_amdgcn_mfma_f32_16x16x32_bf16(qa[nn][u], xm,  are[nn][jt], 0, 0, 0); \
                    aim[nn][jt] = __builtin_amdgcn_mfma_f32_16x16x32_bf16(pa[nn][u], xm,  aim[nn][jt], 0, 0, 0); \
                    aim[nn][jt] = __builtin_amdgcn_mfma_f32_16x16x32_bf16(qa[nn][u], xrn, aim[nn][jt], 0, 0, 0); \
                }                                                               \
            }                                                                   \
        }                                                                       \
        _Pragma("unroll")                                                       \
        for (int nn = 0; nn < 2; ++nn) {                                        \
            _Pragma("unroll")                                                   \
            for (int jt = 0; jt < 2; ++jt) {                                    \
                const bf16x8 kv = kwp[nn][(((p_) & 1) << 1) + jt];              \
                _Pragma("unroll")                                               \
                for (int r = 0; r < 4; ++r) {                                   \
                    reS[nn][r] += are[nn][jt][r] * (float)kv[2 * r]             \
                                - aim[nn][jt][r] * (float)kv[2 * r + 1];        \
                }                                                               \
            }                                                                   \
        }                                                                       \
    }

#define REDUCE_RES()                                                            \
    _Pragma("unroll")                                                           \
    for (int nn = 0; nn < 2; ++nn) {                                            \
        _Pragma("unroll")                                                       \
        for (int r = 0; r < 4; ++r) {                                           \
            reS[nn][r] += __shfl_xor(reS[nn][r], 1);                            \
            reS[nn][r] += __shfl_xor(reS[nn][r], 2);                            \
            reS[nn][r] += __shfl_xor(reS[nn][r], 4);                            \
            reS[nn][r] += __shfl_xor(reS[nn][r], 8);                            \
        }                                                                       \
    }

    // prologue: stage batch 0 quarters 0,1,2 into bufs 0,1,2
    size_t xb0 = (size_t)bat0 * (EDIM * EDIM);
    STAGE_X(xb0, 0, 0 * XBUF);
    STAGE_X(xb0, 1, 1 * XBUF);
    STAGE_X(xb0, 2, 2 * XBUF);

    float reS[2][4] = {{0.f,0.f,0.f,0.f},{0.f,0.f,0.f,0.f}};
    float* part = (float*)(smem + PART_OFF);   // out-row partial [128] f32
    int m0 = 0, m1 = 1, m2 = 2;                // rotation +1/batch (4 mod 3 = 1)

#pragma unroll 1
    for (int n = 0; n < NBAT; ++n) {
        const size_t xbn  = (size_t)(bat0 + n) * (EDIM * EDIM);
        const size_t xbn1 = xbn + (size_t)(EDIM * EDIM);
        const int    xo0  = m0 * XBUF;
        const int    xo1  = m1 * XBUF;
        const int    xo2  = m2 * XBUF;
        const bool   more = (n < NBAT - 1);

        // p0: q0 (jh0) from m0; stage (n,q3) -> m0
        WAITV(8); BARRIER();
        COMPUTE_FOLD(0, xo0);
        BARRIER();
        STAGE_X(xbn, 3, xo0);

        // p1: q1 (jh0 batch-final) from m1; part-write; stage (n+1,q0) -> m1
        WAITV(8); BARRIER();
        COMPUTE_FOLD(1, xo1);
        if (jh == 0) {
            REDUCE_RES();
            if (li == 0) {
#pragma unroll
                for (int nn = 0; nn < 2; ++nn) {
                    f32x4 o;
                    o[0] = reS[nn][0]; o[1] = reS[nn][1];
                    o[2] = reS[nn][2]; o[3] = reS[nn][3];
                    *(f32x4*)(part + (iw * 2 + nn) * 16 + s * 4) = o;
                }
            }
            reS[0][0]=reS[0][1]=reS[0][2]=reS[0][3]=0.f;
            reS[1][0]=reS[1][1]=reS[1][2]=reS[1][3]=0.f;
        }
        BARRIER();
        if (more) STAGE_X(xbn1, 0, xo1);

        // p2: q2 (jh1) from m2; stage (n+1,q1) -> m2
        if (more) { WAITV(8); } else { WAITV(4); }
        BARRIER();
        COMPUTE_FOLD(2, xo2);
        BARRIER();
        if (more) STAGE_X(xbn1, 1, xo2);

        // p3: q3 (jh1 batch-final) from m0; combine + store; stage (n+1,q2)->m0
        if (more) { WAITV(8); } else { WAITV(0); }
        BARRIER();
        COMPUTE_FOLD(3, xo0);
        if (jh == 1) {
            REDUCE_RES();
            if (li == 0) {
#pragma unroll
                for (int nn = 0; nn < 2; ++nn) {
                    f32x4 pv = *(const f32x4*)(part + (iw * 2 + nn) * 16 + s * 4);
                    int oi = (bat0 + n) * EDIM + (iw * 2 + nn) * 16 + s * 4;
                    if (oi + 3 < nout) {
                        f32x4 o;
                        o[0] = reS[nn][0] + pv[0];
                        o[1] = reS[nn][1] + pv[1];
                        o[2] = reS[nn][2] + pv[2];
                        o[3] = reS[nn][3] + pv[3];
                        *(f32x4*)(out + oi) = o;
                    }
                }
            }
            reS[0][0]=reS[0][1]=reS[0][2]=reS[0][3]=0.f;
            reS[1][0]=reS[1][1]=reS[1][2]=reS[1][3]=0.f;
        }
        BARRIER();
        if (more) STAGE_X(xbn1, 2, xo0);

        int tmp = m0; m0 = m1; m1 = m2; m2 = tmp;
    }
}

extern "C" void kernel_launch(void* const* d_in, const int* in_sizes, int n_in,
                              void* d_out, int out_size, void* d_ws, size_t ws_size,
                              hipStream_t stream) {
    const float* R    = (const float*)d_in[0];
    const float* M    = (const float*)d_in[1];
    const float* Kern = (const float*)d_in[2];
    float*       out  = (float*)d_out;
    const int    B    = in_sizes[0] / (EDIM * EDIM);   // 2048

    hipFuncSetAttribute((const void*)qmeas_kernel,
                        hipFuncAttributeMaxDynamicSharedMemorySize, LDS_BYTES);

    int grid = B / NBAT;   // 256
    qmeas_kernel<<<grid, 512, LDS_BYTES, stream>>>(R, M, Kern, out, out_size);
}